// Round 1
// baseline (493.765 us; speedup 1.0000x reference)
//
#include <hip/hip_runtime.h>
#include <hip/hip_bf16.h>

// FFNPCCNorm: out[n,o] = max( (xc[n]·wc[o]) / (|xc[n]| |wc[o]|), 1e-10 ) + bias[o]
// with xc = x - rowmean(x), wc = w - rowmean(w).
// Identities: sum(wc[o,:]) == 0  =>  xc·wc == x·wc ; 1/|wc| folded into bf16 B;
// 1/|xc| applied fp32 in the epilogue.
//
// v2 structure: persistent 8-wave blocks, fp32 x staged to LDS via async
// global_load_lds (one instruction per 1KB row, coalesced), double-buffered
// with counted s_waitcnt vmcnt(8) + raw s_barriers (loads stay in flight
// across barriers). B fragments (tile-invariant) hoisted to 128 VGPRs ->
// inner loop has no global loads. MFMA operands swapped so each lane owns
// 4 consecutive output columns -> dwordx4 nontemporal stores.

#define K_DIM 256
#define N_OUT 256
#define BM    64            // rows per tile
#define ROW_F 260           // fp32 LDS row stride (1040 B): rows land 4 banks apart
#define TILES 8             // tiles per block
#define NBLK  512           // 512 blocks * 8 tiles * 64 rows = 262144

typedef __attribute__((ext_vector_type(8))) __bf16 bf16x8;
typedef __attribute__((ext_vector_type(4))) float  f32x4;

typedef const __attribute__((address_space(1))) unsigned int* gp1_t;
typedef __attribute__((address_space(3))) unsigned int*       lp3_t;

__device__ __forceinline__ unsigned short f2bf(float f) {
    union { float f; unsigned u; } v; v.f = f;
    unsigned r = v.u + 0x7FFFu + ((v.u >> 16) & 1u);   // RNE
    return (unsigned short)(r >> 16);
}

// One wave per weight row: wc = (w - mean) * rsqrt(sum(wc^2)), stored bf16.
__global__ __launch_bounds__(64) void prep_w(const float* __restrict__ w,
                                             unsigned short* __restrict__ wcb) {
    int o = blockIdx.x;        // 256 rows
    int lane = threadIdx.x;    // 64 lanes, 4 floats each
    f32x4 v = *((const f32x4*)(w + (size_t)o * K_DIM) + lane);
    float s  = v.x + v.y + v.z + v.w;
    float s2 = v.x*v.x + v.y*v.y + v.z*v.z + v.w*v.w;
#pragma unroll
    for (int off = 32; off >= 1; off >>= 1) {
        s  += __shfl_xor(s,  off);
        s2 += __shfl_xor(s2, off);
    }
    float mean  = s * (1.0f / 256.0f);
    float var   = s2 - s * mean;                 // sum((w-mean)^2)
    float scale = rsqrtf(fmaxf(var, 1e-30f));
    ushort4 b;
    b.x = f2bf((v.x - mean) * scale);
    b.y = f2bf((v.y - mean) * scale);
    b.z = f2bf((v.z - mean) * scale);
    b.w = f2bf((v.w - mean) * scale);
    *(ushort4*)(wcb + (size_t)o * K_DIM + lane * 4) = b;
}

__global__ __launch_bounds__(512, 2) void pcc_gemm(const float* __restrict__ x,
                                                   const unsigned short* __restrict__ wcb,
                                                   const float* __restrict__ bias,
                                                   float* __restrict__ out) {
    __shared__ __align__(16) float sb[2][BM * ROW_F];   // 2 x 66560 B fp32 tiles
    __shared__ float nrm[BM];

    const int t    = threadIdx.x;
    const int w    = t >> 6;           // wave 0..7
    const int lane = t & 63;
    const int l15  = lane & 15;
    const int q    = lane >> 4;
    const int wr   = w >> 2;           // 0..1: row half  (32 rows)
    const int wc   = w & 3;            // 0..3: col quarter (64 cols)

    // ---- B fragments for this wave's 64 output cols, all K: resident in VGPRs
    // for the whole block (tile-invariant). 32 x bf16x8 = 128 VGPRs.
    bf16x8 bfrag[8][4];
    {
        const unsigned short* wb = wcb + (size_t)(wc * 64 + l15) * K_DIM + q * 8;
#pragma unroll
        for (int ni = 0; ni < 4; ++ni)
#pragma unroll
            for (int ks = 0; ks < 8; ++ks)
                bfrag[ks][ni] = *(const bf16x8*)(wb + (size_t)(ni * 16) * K_DIM + ks * 32);
    }
    // bias for the 4 consecutive cols this lane owns per ni (swapped-D layout)
    f32x4 bb[4];
#pragma unroll
    for (int ni = 0; ni < 4; ++ni)
        bb[ni] = *(const f32x4*)(bias + wc * 64 + ni * 16 + q * 4);

    const size_t tile0 = (size_t)blockIdx.x * TILES;
    const int myrow = w * 8 + (lane >> 3);   // norm pass: 8 rows/wave, 8 lanes/row
    const int seg   = lane & 7;

    // async-stage tile tt into sb[bufi]: one global_load_lds per row
    // (64 lanes x 16 B = exactly one 1 KB row; uniform LDS base per row -> padded stride OK)
    auto issue = [&](int tt, int bufi) {
        const float* src = x + ((tile0 + tt) * BM + w * 8) * (size_t)K_DIM + lane * 4;
        float* dst = &sb[bufi][(w * 8) * ROW_F];
#pragma unroll
        for (int r = 0; r < 8; ++r)
            __builtin_amdgcn_global_load_lds((gp1_t)(src + (size_t)r * K_DIM),
                                             (lp3_t)(dst + r * ROW_F), 16, 0, 0);
    };

    issue(0, 0);

    for (int tt = 0; tt < TILES; ++tt) {
        const int cur = tt & 1;

        // wait own 8 loads of tile tt (counted: leaves prior-tile stores in flight)
        if (tt == 0) { asm volatile("s_waitcnt vmcnt(0)" ::: "memory"); }
        else         { asm volatile("s_waitcnt vmcnt(8)" ::: "memory"); }
        __builtin_amdgcn_sched_barrier(0);
        __builtin_amdgcn_s_barrier();              // B1: tile tt fully in LDS
        __builtin_amdgcn_sched_barrier(0);

        // prefetch next tile immediately (other buffer; freed by B1 of this iter)
        if (tt + 1 < TILES) issue(tt + 1, cur ^ 1);

        // ---- row norms (fp32 from staged x): 8 lanes x 32 floats per row
        {
            const float* rp = &sb[cur][myrow * ROW_F + seg * 32];
            float s = 0.f, s2 = 0.f;
#pragma unroll
            for (int j = 0; j < 8; ++j) {
                f32x4 v = *(const f32x4*)(rp + j * 4);
                s += v.x + v.y + v.z + v.w;
                s2 = fmaf(v.x, v.x, s2); s2 = fmaf(v.y, v.y, s2);
                s2 = fmaf(v.z, v.z, s2); s2 = fmaf(v.w, v.w, s2);
            }
            s  += __shfl_xor(s, 1);  s  += __shfl_xor(s, 2);  s  += __shfl_xor(s, 4);
            s2 += __shfl_xor(s2, 1); s2 += __shfl_xor(s2, 2); s2 += __shfl_xor(s2, 4);
            if (seg == 0) {
                float var = s2 - s * s * (1.0f / 256.0f);   // sum(xc^2)
                nrm[myrow] = rsqrtf(fmaxf(var, 1e-30f));
            }
        }
        asm volatile("s_waitcnt lgkmcnt(0)" ::: "memory");  // drain nrm ds_write
        __builtin_amdgcn_sched_barrier(0);
        __builtin_amdgcn_s_barrier();              // B2: nrm visible
        __builtin_amdgcn_sched_barrier(0);

        // ---- MFMA: wave owns 32 rows x 64 cols; A read fp32 from LDS, cvt to bf16
        f32x4 acc[2][4];
#pragma unroll
        for (int mi = 0; mi < 2; ++mi)
#pragma unroll
            for (int ni = 0; ni < 4; ++ni)
                acc[mi][ni] = (f32x4){0.f, 0.f, 0.f, 0.f};

        const float* ab = &sb[cur][(wr * 32 + l15) * ROW_F + q * 8];
#pragma unroll
        for (int ks = 0; ks < 8; ++ks) {
#pragma unroll
            for (int mi = 0; mi < 2; ++mi) {
                const float* ap = ab + mi * 16 * ROW_F + ks * 32;
                f32x4 lo = *(const f32x4*)ap;
                f32x4 hi = *(const f32x4*)(ap + 4);
                bf16x8 a;
                a[0] = (__bf16)lo.x; a[1] = (__bf16)lo.y;
                a[2] = (__bf16)lo.z; a[3] = (__bf16)lo.w;
                a[4] = (__bf16)hi.x; a[5] = (__bf16)hi.y;
                a[6] = (__bf16)hi.z; a[7] = (__bf16)hi.w;
#pragma unroll
                for (int ni = 0; ni < 4; ++ni)   // swapped operands: D row-dim = weight rows
                    acc[mi][ni] = __builtin_amdgcn_mfma_f32_16x16x32_bf16(
                        bfrag[ks][ni], a, acc[mi][ni], 0, 0, 0);
            }
        }

        // ---- epilogue: lane(q,l15) reg r = out[row + mi*16 + l15][wc*64 + ni*16 + q*4 + r]
        const size_t grow = (tile0 + tt) * BM + wr * 32 + l15;
#pragma unroll
        for (int mi = 0; mi < 2; ++mi) {
            const float inv = nrm[wr * 32 + mi * 16 + l15];   // lane-uniform over regs
            float* op = out + (grow + (size_t)mi * 16) * N_OUT + wc * 64 + q * 4;
#pragma unroll
            for (int ni = 0; ni < 4; ++ni) {
                f32x4 vx;
#pragma unroll
                for (int r = 0; r < 4; ++r)
                    vx[r] = fmaxf(acc[mi][ni][r] * inv, 1e-10f) + bb[ni][r];
                __builtin_nontemporal_store(vx, (f32x4*)(op + ni * 16));
            }
        }
        // no trailing barrier: next iteration's B1 orders buffer reuse
    }
}

extern "C" void kernel_launch(void* const* d_in, const int* in_sizes, int n_in,
                              void* d_out, int out_size, void* d_ws, size_t ws_size,
                              hipStream_t stream) {
    const float* x    = (const float*)d_in[0];   // [262144, 256]
    const float* w    = (const float*)d_in[1];   // [256, 256]
    const float* bias = (const float*)d_in[2];   // [256]
    float* out = (float*)d_out;                  // [262144, 256]
    unsigned short* wcb = (unsigned short*)d_ws; // 128 KB bf16 wc (scaled)

    prep_w<<<256, 64, 0, stream>>>(w, wcb);
    pcc_gemm<<<NBLK, 512, 0, stream>>>(x, wcb, bias, out);
}